// Round 4
// baseline (238.169 us; speedup 1.0000x reference)
//
#include <hip/hip_runtime.h>
#include <math.h>

#define D_EMB 256
#define NHEAD 8
#define HD 32
#define NG 64
#define ATT_SCALE 0.17677669529663687f  // 1/sqrt(32)

typedef __attribute__((ext_vector_type(8))) short short8b;   // 8 bf16 (4 VGPR)
typedef __attribute__((ext_vector_type(4))) float f32x4;

__device__ __forceinline__ unsigned short f2bf(float x) {
    unsigned int u = __builtin_bit_cast(unsigned int, x);
    unsigned int r = (u + 0x7FFFu + ((u >> 16) & 1u)) >> 16;
    return (unsigned short)r;
}

// ---------------- meta: starts / counts from sorted batch ----------------
__global__ void k_starts(const int* __restrict__ batch, int n, int* __restrict__ starts) {
    int i = blockIdx.x * blockDim.x + threadIdx.x;
    if (i >= n) return;
    int b = batch[i];
    if (i == 0 || batch[i - 1] != b) starts[b] = i;
}

__global__ void k_counts(const int* __restrict__ starts, int n, int* __restrict__ counts) {
    int g = threadIdx.x;
    if (g < NG) {
        int s = starts[g];
        int e = (g == NG - 1) ? n : starts[g + 1];
        counts[g] = e - s;
    }
}

// ---------------- fp32 -> bf16 bulk convert --------------------------------
__global__ void k_f2bf4(const float* __restrict__ src, unsigned short* __restrict__ dst, int n4) {
    int i = blockIdx.x * blockDim.x + threadIdx.x;
    if (i >= n4) return;
    float4 v = ((const float4*)src)[i];
    ushort4 o;
    o.x = f2bf(v.x); o.y = f2bf(v.y); o.z = f2bf(v.z); o.w = f2bf(v.w);
    ((ushort4*)dst)[i] = o;
}

// ---------------- direct-global bf16 MFMA GEMM (no LDS, no barriers) -------
// C = A(MxK=256) * W(Nx256)^T.  128x128 tile, 4 waves (2x2), 4x4 MFMA/wave.
// MODE 0: fp32 out + bias + resid.  MODE 1: bf16 out split into Q/K/V by col.
template<int MODE>
__global__ __launch_bounds__(256) void k_gemm_direct(
    const unsigned short* __restrict__ A, const unsigned short* __restrict__ W,
    const float* __restrict__ bias, const float* __restrict__ resid,
    float* __restrict__ Cf, unsigned short* __restrict__ Qb,
    unsigned short* __restrict__ Kb, unsigned short* __restrict__ Vb,
    int M, int Ncols) {
    int tid = threadIdx.x;
    int wave = tid >> 6, lane = tid & 63;
    int lrow = lane & 15, lgrp = lane >> 4;
    int wr = wave >> 1, wc = wave & 1;
    int row0 = blockIdx.x * 128, col0 = blockIdx.y * 128;

    int arow[4];
#pragma unroll
    for (int mi = 0; mi < 4; ++mi) {
        int r = row0 + wr * 64 + mi * 16 + lrow;
        arow[mi] = r < M ? r : (M - 1);
    }
    int bcol0 = col0 + wc * 64 + lrow;

    f32x4 acc[4][4];
#pragma unroll
    for (int i = 0; i < 4; ++i)
#pragma unroll
        for (int j = 0; j < 4; ++j) acc[i][j] = (f32x4){0.f, 0.f, 0.f, 0.f};

#pragma unroll
    for (int k0 = 0; k0 < 256; k0 += 32) {
        short8b af[4], bf[4];
#pragma unroll
        for (int mi = 0; mi < 4; ++mi)
            af[mi] = *(const short8b*)&A[(size_t)arow[mi] * 256 + k0 + lgrp * 8];
#pragma unroll
        for (int ni = 0; ni < 4; ++ni)
            bf[ni] = *(const short8b*)&W[(size_t)(bcol0 + ni * 16) * 256 + k0 + lgrp * 8];
#pragma unroll
        for (int mi = 0; mi < 4; ++mi)
#pragma unroll
            for (int ni = 0; ni < 4; ++ni)
                acc[mi][ni] = __builtin_amdgcn_mfma_f32_16x16x32_bf16(
                    af[mi], bf[ni], acc[mi][ni], 0, 0, 0);
    }

    if (MODE == 0) {
#pragma unroll
        for (int ni = 0; ni < 4; ++ni) {
            int col = col0 + wc * 64 + ni * 16 + lrow;
            float bv = bias[col];
#pragma unroll
            for (int mi = 0; mi < 4; ++mi) {
                int rowb = row0 + wr * 64 + mi * 16 + lgrp * 4;
#pragma unroll
                for (int r = 0; r < 4; ++r) {
                    int row = rowb + r;
                    if (row < M) {
                        float v = acc[mi][ni][r] + bv;
                        if (resid) v += resid[(size_t)row * Ncols + col];
                        Cf[(size_t)row * Ncols + col] = v;
                    }
                }
            }
        }
    } else {
        int sel = blockIdx.y >> 1;  // 0:Q 1:K 2:V (col0 never straddles 256-blocks)
        unsigned short* dst = sel == 0 ? Qb : (sel == 1 ? Kb : Vb);
#pragma unroll
        for (int ni = 0; ni < 4; ++ni) {
            int colg = col0 + wc * 64 + ni * 16 + lrow;
            int col = colg & 255;
            float bv = bias[colg];
#pragma unroll
            for (int mi = 0; mi < 4; ++mi) {
                int rowb = row0 + wr * 64 + mi * 16 + lgrp * 4;
#pragma unroll
                for (int r = 0; r < 4; ++r) {
                    int row = rowb + r;
                    if (row < M)
                        dst[(size_t)row * 256 + col] = f2bf(acc[mi][ni][r] + bv);
                }
            }
        }
    }
}

// ---------------- MFMA attention, all-bf16 inputs --------------------------
// block = (graph, head, 128-q chunk); 4 waves x 32 q; 32-key tiles.
// S^T = mfma(K, Q); K frags direct from global; V^T double-buffered in LDS.
#define LSW 40  // LDS row stride in ushort (80 B)

__global__ __launch_bounds__(256) void k_attn2(
    const unsigned short* __restrict__ Qb, const unsigned short* __restrict__ Kb,
    const unsigned short* __restrict__ Vb, const int* __restrict__ starts,
    const int* __restrict__ counts, unsigned short* __restrict__ ctxb) {
    int g = blockIdx.x, h = blockIdx.y, chunk = blockIdx.z;
    int L = counts[g], s0 = starts[g];
    if (chunk * 128 >= L) return;

    __shared__ __align__(16) unsigned short Vt[2][HD][LSW];

    int tid = threadIdx.x;
    int wave = tid >> 6, lane = tid & 63;
    int lrow = lane & 15, lgrp = lane >> 4;
    int qbase = chunk * 128 + wave * 32;

    // Q fragments (B-operand), direct global bf16
    short8b qfrag[2];
#pragma unroll
    for (int qm = 0; qm < 2; ++qm) {
        int qr = qbase + qm * 16 + lrow;
        if (qr >= L) qr = L - 1;
        qfrag[qm] = *(const short8b*)&Qb[(size_t)(s0 + qr) * 256 + h * HD + lgrp * 8];
    }

    // staging indices for V^T (permuted cols sigma(key))
    int key = tid >> 3;
    int d4 = (tid & 7) * 4;
    int sigc = ((key >> 2) & 3) * 8 + ((key >> 4) & 1) * 4 + (key & 3);

    int ntiles = (L + 31) >> 5;

    // prologue: tile 0 K frags + V stage
    short8b kf[2], kfn[2];
#pragma unroll
    for (int kn = 0; kn < 2; ++kn) {
        int kr = kn * 16 + lrow;
        if (kr >= L) kr = L - 1;
        kf[kn] = *(const short8b*)&Kb[(size_t)(s0 + kr) * 256 + h * HD + lgrp * 8];
    }
    {
        int kr = key < L ? key : (L - 1);
        ushort4 vr = *(const ushort4*)&Vb[(size_t)(s0 + kr) * 256 + h * HD + d4];
        Vt[0][d4 + 0][sigc] = vr.x;
        Vt[0][d4 + 1][sigc] = vr.y;
        Vt[0][d4 + 2][sigc] = vr.z;
        Vt[0][d4 + 3][sigc] = vr.w;
    }

    float mrun[2] = {-INFINITY, -INFINITY};
    float lrun[2] = {0.f, 0.f};
    f32x4 acc[2][2];
#pragma unroll
    for (int a = 0; a < 2; ++a)
#pragma unroll
        for (int b = 0; b < 2; ++b) acc[a][b] = (f32x4){0.f, 0.f, 0.f, 0.f};

    for (int t = 0; t < ntiles; ++t) {
        int kt = t * 32;
        __syncthreads();  // Vt[t&1] ready

        short8b vf[2];
        vf[0] = *(const short8b*)&Vt[t & 1][lrow][lgrp * 8];
        vf[1] = *(const short8b*)&Vt[t & 1][16 + lrow][lgrp * 8];

        // prefetch next tile (issue early; latency hidden under compute)
        bool more = (t + 1) < ntiles;
        ushort4 vrn;
        if (more) {
            int ktn = kt + 32;
#pragma unroll
            for (int kn = 0; kn < 2; ++kn) {
                int kr = ktn + kn * 16 + lrow;
                if (kr >= L) kr = L - 1;
                kfn[kn] = *(const short8b*)&Kb[(size_t)(s0 + kr) * 256 + h * HD + lgrp * 8];
            }
            int kr = ktn + key;
            if (kr >= L) kr = L - 1;
            vrn = *(const ushort4*)&Vb[(size_t)(s0 + kr) * 256 + h * HD + d4];
        }

        // S^T[key][q]
        f32x4 s[2][2];
#pragma unroll
        for (int kn = 0; kn < 2; ++kn)
#pragma unroll
            for (int qm = 0; qm < 2; ++qm)
                s[kn][qm] = __builtin_amdgcn_mfma_f32_16x16x32_bf16(
                    kf[kn], qfrag[qm], (f32x4){0.f, 0.f, 0.f, 0.f}, 0, 0, 0);

        // online softmax (8 scores/lane per qm; reduce across lgrp: 2 shuffles)
        float p[2][2][4];
#pragma unroll
        for (int qm = 0; qm < 2; ++qm) {
            float mx = -INFINITY;
#pragma unroll
            for (int kn = 0; kn < 2; ++kn)
#pragma unroll
                for (int r = 0; r < 4; ++r) {
                    bool ok = (kt + kn * 16 + lgrp * 4 + r) < L;
                    float sc = ok ? s[kn][qm][r] * ATT_SCALE : -INFINITY;
                    p[qm][kn][r] = sc;
                    mx = fmaxf(mx, sc);
                }
            mx = fmaxf(mx, __shfl_xor(mx, 16));
            mx = fmaxf(mx, __shfl_xor(mx, 32));
            float mnew = fmaxf(mrun[qm], mx);
            float fsc = __expf(mrun[qm] - mnew);
            mrun[qm] = mnew;
            float ps = 0.f;
#pragma unroll
            for (int kn = 0; kn < 2; ++kn)
#pragma unroll
                for (int r = 0; r < 4; ++r) {
                    float pv = __expf(p[qm][kn][r] - mnew);
                    p[qm][kn][r] = pv;
                    ps += pv;
                }
            ps += __shfl_xor(ps, 16);
            ps += __shfl_xor(ps, 32);
            lrun[qm] = lrun[qm] * fsc + ps;
#pragma unroll
            for (int dsub = 0; dsub < 2; ++dsub)
#pragma unroll
                for (int r = 0; r < 4; ++r) acc[qm][dsub][r] *= fsc;
        }

        // pack P as B-operand (key order matches sigma-permuted V^T cols)
        short8b pf[2];
#pragma unroll
        for (int qm = 0; qm < 2; ++qm) {
            short8b tt;
            tt[0] = (short)f2bf(p[qm][0][0]); tt[1] = (short)f2bf(p[qm][0][1]);
            tt[2] = (short)f2bf(p[qm][0][2]); tt[3] = (short)f2bf(p[qm][0][3]);
            tt[4] = (short)f2bf(p[qm][1][0]); tt[5] = (short)f2bf(p[qm][1][1]);
            tt[6] = (short)f2bf(p[qm][1][2]); tt[7] = (short)f2bf(p[qm][1][3]);
            pf[qm] = tt;
        }

        // PV: O^T += V^T P^T
#pragma unroll
        for (int dsub = 0; dsub < 2; ++dsub)
#pragma unroll
            for (int qm = 0; qm < 2; ++qm)
                acc[qm][dsub] = __builtin_amdgcn_mfma_f32_16x16x32_bf16(
                    vf[dsub], pf[qm], acc[qm][dsub], 0, 0, 0);

        // stage next tile into the other buffer (no extra barrier needed)
        if (more) {
            int nb = (t + 1) & 1;
            Vt[nb][d4 + 0][sigc] = vrn.x;
            Vt[nb][d4 + 1][sigc] = vrn.y;
            Vt[nb][d4 + 2][sigc] = vrn.z;
            Vt[nb][d4 + 3][sigc] = vrn.w;
            kf[0] = kfn[0];
            kf[1] = kfn[1];
        }
    }

    // epilogue: ctx bf16, packed u32 stores
#pragma unroll
    for (int qm = 0; qm < 2; ++qm) {
        int q = qbase + qm * 16 + lrow;
        if (q >= L) continue;
        float inv = 1.f / lrun[qm];
        unsigned short* dst = ctxb + (size_t)(s0 + q) * 256 + h * HD;
#pragma unroll
        for (int dsub = 0; dsub < 2; ++dsub) {
#pragma unroll
            for (int rp = 0; rp < 4; rp += 2) {
                unsigned int w =
                    (unsigned int)f2bf(acc[qm][dsub][rp] * inv) |
                    ((unsigned int)f2bf(acc[qm][dsub][rp + 1] * inv) << 16);
                *(unsigned int*)&dst[dsub * 16 + lgrp * 4 + rp] = w;
            }
        }
    }
}

// ---------------- per-graph LN stats (graph mode) --------------------------
__global__ __launch_bounds__(256) void k_stats(
    const float* __restrict__ hbuf, const int* __restrict__ starts,
    const int* __restrict__ counts, float* __restrict__ stats) {
    int g = blockIdx.x;
    int s0 = starts[g];
    int cnt = counts[g];
    size_t total4 = (size_t)cnt * (D_EMB / 4);
    const float4* p = (const float4*)(hbuf + (size_t)s0 * D_EMB);

    float sum = 0.f, sq = 0.f;
    for (size_t i = threadIdx.x; i < total4; i += 256) {
        float4 v = p[i];
        sum += v.x + v.y + v.z + v.w;
        sq += v.x * v.x + v.y * v.y + v.z * v.z + v.w * v.w;
    }
#pragma unroll
    for (int o = 32; o > 0; o >>= 1) {
        sum += __shfl_down(sum, o);
        sq += __shfl_down(sq, o);
    }
    __shared__ float ssum[4], ssq[4];
    int wid = threadIdx.x >> 6, lane = threadIdx.x & 63;
    if (lane == 0) { ssum[wid] = sum; ssq[wid] = sq; }
    __syncthreads();
    if (threadIdx.x == 0) {
        float S = 0.f, Q = 0.f;
#pragma unroll
        for (int w = 0; w < 4; ++w) { S += ssum[w]; Q += ssq[w]; }
        float norm = (float)cnt * (float)D_EMB;
        float mean = S / norm;
        float var = Q / norm - mean * mean;
        stats[g * 2] = mean;
        stats[g * 2 + 1] = rsqrtf(var + 1e-5f);
    }
}

// ---------------- LN apply + exact GELU, in place --------------------------
__global__ void k_ln_gelu(float* __restrict__ h, const int* __restrict__ batch,
                          const float* __restrict__ stats, const float* __restrict__ lw,
                          const float* __restrict__ lb, int n) {
    int idx = blockIdx.x * blockDim.x + threadIdx.x;
    if (idx >= n * (D_EMB / 4)) return;
    int row = idx >> 6;
    int c4 = idx & 63;
    int g = batch[row];
    float mean = stats[2 * g], inv = stats[2 * g + 1];
    float4 v = *(float4*)&h[(size_t)idx * 4];
    float4 wv = *(const float4*)&lw[c4 * 4];
    float4 bv = *(const float4*)&lb[c4 * 4];
    float y;
    y = (v.x - mean) * inv * wv.x + bv.x; v.x = 0.5f * y * (1.f + erff(y * 0.70710678118f));
    y = (v.y - mean) * inv * wv.y + bv.y; v.y = 0.5f * y * (1.f + erff(y * 0.70710678118f));
    y = (v.z - mean) * inv * wv.z + bv.z; v.z = 0.5f * y * (1.f + erff(y * 0.70710678118f));
    y = (v.w - mean) * inv * wv.w + bv.w; v.w = 0.5f * y * (1.f + erff(y * 0.70710678118f));
    *(float4*)&h[(size_t)idx * 4] = v;
}

// ---------------- launch ----------------------------------------------------
extern "C" void kernel_launch(void* const* d_in, const int* in_sizes, int n_in,
                              void* d_out, int out_size, void* d_ws, size_t ws_size,
                              hipStream_t stream) {
    const float* x     = (const float*)d_in[0];
    const int*   batch = (const int*)d_in[1];
    const float* in_w  = (const float*)d_in[2];
    const float* in_b  = (const float*)d_in[3];
    const float* out_w = (const float*)d_in[4];
    const float* out_b = (const float*)d_in[5];
    const float* ln_w  = (const float*)d_in[6];
    const float* ln_b  = (const float*)d_in[7];
    int N = in_sizes[1];
    float* out = (float*)d_out;

    char* ws = (char*)d_ws;
    int*   starts = (int*)ws;                       // 64
    int*   counts = starts + 64;                    // 64
    float* stats  = (float*)(ws + 512);             // 128 floats
    unsigned short* xb   = (unsigned short*)(ws + 1024);
    unsigned short* wb1  = xb + (size_t)N * 256;    // 768*256
    unsigned short* wb2  = wb1 + 768 * 256;         // 256*256
    unsigned short* Qb   = wb2 + 256 * 256;
    unsigned short* Kb   = Qb + (size_t)N * 256;
    unsigned short* Vb   = Kb + (size_t)N * 256;
    unsigned short* ctxb = Vb + (size_t)N * 256;

    k_starts<<<(N + 255) / 256, 256, 0, stream>>>(batch, N, starts);
    k_counts<<<1, 64, 0, stream>>>(starts, N, counts);

    int n4x = N * 64;
    k_f2bf4<<<(n4x + 255) / 256, 256, 0, stream>>>(x, xb, n4x);
    k_f2bf4<<<(768 * 64 + 255) / 256, 256, 0, stream>>>(in_w, wb1, 768 * 64);
    k_f2bf4<<<(256 * 64 + 255) / 256, 256, 0, stream>>>(out_w, wb2, 256 * 64);

    dim3 g1((N + 127) / 128, 6);
    k_gemm_direct<1><<<g1, 256, 0, stream>>>(xb, wb1, in_b, nullptr, nullptr,
                                             Qb, Kb, Vb, N, 768);

    k_attn2<<<dim3(NG, NHEAD, 4), 256, 0, stream>>>(Qb, Kb, Vb, starts, counts, ctxb);

    dim3 g3((N + 127) / 128, 2);
    k_gemm_direct<0><<<g3, 256, 0, stream>>>(ctxb, wb2, out_b, x, out,
                                             nullptr, nullptr, nullptr, N, 256);

    k_stats<<<NG, 256, 0, stream>>>(out, starts, counts, stats);

    int nv4 = N * (D_EMB / 4);
    k_ln_gelu<<<(nv4 + 255) / 256, 256, 0, stream>>>(out, batch, stats, ln_w, ln_b, N);
}

// Round 6
// 226.766 us; speedup vs baseline: 1.0503x; 1.0503x over previous
//
#include <hip/hip_runtime.h>
#include <hip/hip_bf16.h>
#include <math.h>

#define D_EMB 256
#define NHEAD 8
#define HD 32
#define NG 64
// 1/sqrt(32) * log2(e): softmax runs in exp2 domain, scale folded into Q
#define QSC 0.25503486f

typedef __attribute__((ext_vector_type(8))) short short8b;   // 8 bf16 (4 VGPR)
typedef __attribute__((ext_vector_type(4))) float f32x4;

__device__ __forceinline__ unsigned int pk2(float a, float b) {
    union { __hip_bfloat162 t; unsigned int u; } r;
    r.t = __float22bfloat162_rn(make_float2(a, b));
    return r.u;
}

__device__ __forceinline__ short8b pack8f(const float* v) {
    union { unsigned int u[4]; short8b s; } r;
    r.u[0] = pk2(v[0], v[1]);
    r.u[1] = pk2(v[2], v[3]);
    r.u[2] = pk2(v[4], v[5]);
    r.u[3] = pk2(v[6], v[7]);
    return r.s;
}

// ---------------- meta: starts / counts from sorted batch ----------------
__global__ void k_starts(const int* __restrict__ batch, int n, int* __restrict__ starts) {
    int i = blockIdx.x * blockDim.x + threadIdx.x;
    if (i >= n) return;
    int b = batch[i];
    if (i == 0 || batch[i - 1] != b) starts[b] = i;
}

__global__ void k_counts(const int* __restrict__ starts, int n, int* __restrict__ counts) {
    int g = threadIdx.x;
    if (g < NG) {
        int s = starts[g];
        int e = (g == NG - 1) ? n : starts[g + 1];
        counts[g] = e - s;
    }
}

// ---------------- fp32 -> bf16 bulk convert --------------------------------
__global__ void k_f2bf4(const float* __restrict__ src, unsigned short* __restrict__ dst, int n4) {
    int i = blockIdx.x * blockDim.x + threadIdx.x;
    if (i >= n4) return;
    float4 v = ((const float4*)src)[i];
    uint2 o;
    o.x = pk2(v.x, v.y);
    o.y = pk2(v.z, v.w);
    ((uint2*)dst)[i] = o;
}

// ---------------- bf16 LDS-staged MFMA GEMM --------------------------------
// C = A(Mx256) * W(Nx256)^T.  128x128 tile, 4 waves (2x2), BK=64.
// MODE 0: fp32 out + bias + resid.  MODE 1: bf16 Q(pre-scaled)/K/V split.
#define GLSW 72  // LDS row stride in ushort (144 B)

template<int MODE>
__global__ __launch_bounds__(256) void k_gemm(
    const unsigned short* __restrict__ A, const unsigned short* __restrict__ W,
    const float* __restrict__ bias, const float* __restrict__ resid,
    float* __restrict__ Cf, unsigned short* __restrict__ Qb,
    unsigned short* __restrict__ Kb, unsigned short* __restrict__ Vb,
    int M, int Ncols) {
    __shared__ __align__(16) unsigned short Al[128][GLSW];
    __shared__ __align__(16) unsigned short Bl[128][GLSW];

    int tid = threadIdx.x;
    int wave = tid >> 6, lane = tid & 63;
    int lrow = lane & 15, lgrp = lane >> 4;
    int wr = wave >> 1, wc = wave & 1;
    int row0 = blockIdx.x * 128, col0 = blockIdx.y * 128;

    f32x4 acc[4][4];
#pragma unroll
    for (int i = 0; i < 4; ++i)
#pragma unroll
        for (int j = 0; j < 4; ++j) acc[i][j] = (f32x4){0.f, 0.f, 0.f, 0.f};

    for (int k0 = 0; k0 < 256; k0 += 64) {
#pragma unroll
        for (int p = 0; p < 4; ++p) {
            int idx = tid + p * 256;
            int r = idx >> 3, c = (idx & 7) * 8;
            int ar = row0 + r; if (ar >= M) ar = M - 1;
            *(short8b*)&Al[r][c] = *(const short8b*)&A[(size_t)ar * 256 + k0 + c];
            *(short8b*)&Bl[r][c] = *(const short8b*)&W[(size_t)(col0 + r) * 256 + k0 + c];
        }
        __syncthreads();
#pragma unroll
        for (int half = 0; half < 2; ++half) {
            short8b af[4], bf[4];
#pragma unroll
            for (int mi = 0; mi < 4; ++mi)
                af[mi] = *(const short8b*)&Al[wr * 64 + mi * 16 + lrow][half * 32 + lgrp * 8];
#pragma unroll
            for (int ni = 0; ni < 4; ++ni)
                bf[ni] = *(const short8b*)&Bl[wc * 64 + ni * 16 + lrow][half * 32 + lgrp * 8];
#pragma unroll
            for (int mi = 0; mi < 4; ++mi)
#pragma unroll
                for (int ni = 0; ni < 4; ++ni)
                    acc[mi][ni] = __builtin_amdgcn_mfma_f32_16x16x32_bf16(
                        af[mi], bf[ni], acc[mi][ni], 0, 0, 0);
        }
        __syncthreads();
    }

    if (MODE == 0) {
#pragma unroll
        for (int ni = 0; ni < 4; ++ni) {
            int col = col0 + wc * 64 + ni * 16 + lrow;
            float bv = bias[col];
#pragma unroll
            for (int mi = 0; mi < 4; ++mi) {
                int rowb = row0 + wr * 64 + mi * 16 + lgrp * 4;
#pragma unroll
                for (int r = 0; r < 4; ++r) {
                    int row = rowb + r;
                    if (row < M) {
                        float v = acc[mi][ni][r] + bv;
                        v += resid[(size_t)row * Ncols + col];
                        Cf[(size_t)row * Ncols + col] = v;
                    }
                }
            }
        }
    } else {
        int sel = blockIdx.y >> 1;  // 0:Q 1:K 2:V
        unsigned short* dst = sel == 0 ? Qb : (sel == 1 ? Kb : Vb);
        float qsc = sel == 0 ? QSC : 1.f;
#pragma unroll
        for (int ni = 0; ni < 4; ++ni) {
            int colg = col0 + wc * 64 + ni * 16 + lrow;
            int col = colg & 255;
            float bv = bias[colg];
#pragma unroll
            for (int mi = 0; mi < 4; ++mi) {
                int rowb = row0 + wr * 64 + mi * 16 + lgrp * 4;
#pragma unroll
                for (int r = 0; r < 4; ++r) {
                    int row = rowb + r;
                    if (row < M) {
                        union { __hip_bfloat16 b; unsigned short u; } cv;
                        cv.b = __float2bfloat16((acc[mi][ni][r] + bv) * qsc);
                        dst[(size_t)row * 256 + col] = cv.u;
                    }
                }
            }
        }
    }
}

// ---------------- MFMA attention: block = (graph, head) --------------------
// K + V^T staged in LDS once (75 KB, 2 blocks/CU); main loop barrier-free.
// Each wave owns 64 q rows; S^T = mfma(K, Qscaled); softmax in exp2 domain.
__global__ __launch_bounds__(256) void k_attn3(
    const unsigned short* __restrict__ Qb, const unsigned short* __restrict__ Kb,
    const unsigned short* __restrict__ Vb, const int* __restrict__ starts,
    const int* __restrict__ counts, unsigned short* __restrict__ ctxb) {
    int g = blockIdx.x, h = blockIdx.y;
    int L = counts[g], s0 = starts[g];
    int Lpad = (L + 31) & ~31;

    __shared__ __align__(16) unsigned short Klds[512][40];  // 40960 B
    __shared__ __align__(16) unsigned short Vt[32][536];    // 34304 B

    int tid = threadIdx.x;
    int wave = tid >> 6, lane = tid & 63;
    int lrow = lane & 15, lgrp = lane >> 4;

    // ---- stage K (row-major, zero-padded rows) ----
    for (int idx = tid; idx < L * 4; idx += 256) {
        int key = idx >> 2, c = (idx & 3) * 8;
        *(short8b*)&Klds[key][c] = *(const short8b*)&Kb[(size_t)(s0 + key) * 256 + h * 32 + c];
    }
    for (int idx = L * 4 + tid; idx < Lpad * 4; idx += 256) {
        int key = idx >> 2, c = (idx & 3) * 8;
        *(short8b*)&Klds[key][c] = (short8b){0, 0, 0, 0, 0, 0, 0, 0};
    }
    // ---- stage V^T with sigma-permuted columns (per 32-key group) ----
    for (int idx = tid; idx < L * 8; idx += 256) {
        int key = idx >> 3, d4 = (idx & 7) * 4;
        ushort4 v = *(const ushort4*)&Vb[(size_t)(s0 + key) * 256 + h * 32 + d4];
        int k5 = key & 31;
        int c = (key & ~31) + ((k5 >> 2) & 3) * 8 + (k5 >> 4) * 4 + (k5 & 3);
        Vt[d4 + 0][c] = v.x; Vt[d4 + 1][c] = v.y;
        Vt[d4 + 2][c] = v.z; Vt[d4 + 3][c] = v.w;
    }
    for (int idx = L * 8 + tid; idx < Lpad * 8; idx += 256) {
        int key = idx >> 3, d4 = (idx & 7) * 4;
        int k5 = key & 31;
        int c = (key & ~31) + ((k5 >> 2) & 3) * 8 + (k5 >> 4) * 4 + (k5 & 3);
        Vt[d4 + 0][c] = 0; Vt[d4 + 1][c] = 0;
        Vt[d4 + 2][c] = 0; Vt[d4 + 3][c] = 0;
    }
    __syncthreads();

    int nkt = Lpad >> 5;
    int nfull = L >> 5;
    int ntq = (L + 63) >> 6;

    for (int qt = wave; qt < ntq; qt += 4) {
        int qbase = qt * 64;
        short8b qf[4];
#pragma unroll
        for (int qm = 0; qm < 4; ++qm) {
            int qr = qbase + qm * 16 + lrow;
            if (qr >= L) qr = L - 1;  // clamp; output discarded
            qf[qm] = *(const short8b*)&Qb[(size_t)(s0 + qr) * 256 + h * 32 + lgrp * 8];
        }
        float mrun[4] = {-INFINITY, -INFINITY, -INFINITY, -INFINITY};
        float lrun[4] = {0.f, 0.f, 0.f, 0.f};
        f32x4 acc[4][2];
#pragma unroll
        for (int a = 0; a < 4; ++a) {
            acc[a][0] = (f32x4){0.f, 0.f, 0.f, 0.f};
            acc[a][1] = (f32x4){0.f, 0.f, 0.f, 0.f};
        }

        for (int t = 0; t < nkt; ++t) {
            int kt = t * 32;
            short8b kf0 = *(const short8b*)&Klds[kt + lrow][lgrp * 8];
            short8b kf1 = *(const short8b*)&Klds[kt + 16 + lrow][lgrp * 8];
            bool tail = (t >= nfull);

            f32x4 sv0[4], sv1[4];
#pragma unroll
            for (int qm = 0; qm < 4; ++qm) {
                sv0[qm] = __builtin_amdgcn_mfma_f32_16x16x32_bf16(
                    kf0, qf[qm], (f32x4){0.f, 0.f, 0.f, 0.f}, 0, 0, 0);
                sv1[qm] = __builtin_amdgcn_mfma_f32_16x16x32_bf16(
                    kf1, qf[qm], (f32x4){0.f, 0.f, 0.f, 0.f}, 0, 0, 0);
            }

            short8b pf[4];
#pragma unroll
            for (int qm = 0; qm < 4; ++qm) {
                float sc[8];
#pragma unroll
                for (int r = 0; r < 4; ++r) { sc[r] = sv0[qm][r]; sc[4 + r] = sv1[qm][r]; }
                if (tail) {
#pragma unroll
                    for (int j = 0; j < 8; ++j) {
                        int key = kt + (j >> 2) * 16 + lgrp * 4 + (j & 3);
                        if (key >= L) sc[j] = -INFINITY;
                    }
                }
                float mx = fmaxf(fmaxf(fmaxf(sc[0], sc[1]), fmaxf(sc[2], sc[3])),
                                 fmaxf(fmaxf(sc[4], sc[5]), fmaxf(sc[6], sc[7])));
                mx = fmaxf(mx, __shfl_xor(mx, 16));
                mx = fmaxf(mx, __shfl_xor(mx, 32));
                float mq = mrun[qm];
                if (!__all(mx <= mq)) {  // exact skip: if no lane grew, fsc==1
                    float mnew = fmaxf(mq, mx);
                    float fs = exp2f(mq - mnew);
                    lrun[qm] *= fs;
#pragma unroll
                    for (int e = 0; e < 4; ++e) { acc[qm][0][e] *= fs; acc[qm][1][e] *= fs; }
                    mrun[qm] = mnew;
                    mq = mnew;
                }
                float pv[8];
                float ps = 0.f;
#pragma unroll
                for (int j = 0; j < 8; ++j) { pv[j] = exp2f(sc[j] - mq); ps += pv[j]; }
                ps += __shfl_xor(ps, 16);
                ps += __shfl_xor(ps, 32);
                lrun[qm] += ps;
                pf[qm] = pack8f(pv);
            }

            short8b vf0 = *(const short8b*)&Vt[lrow][kt + lgrp * 8];
            short8b vf1 = *(const short8b*)&Vt[16 + lrow][kt + lgrp * 8];
#pragma unroll
            for (int qm = 0; qm < 4; ++qm) {
                acc[qm][0] = __builtin_amdgcn_mfma_f32_16x16x32_bf16(vf0, pf[qm], acc[qm][0], 0, 0, 0);
                acc[qm][1] = __builtin_amdgcn_mfma_f32_16x16x32_bf16(vf1, pf[qm], acc[qm][1], 0, 0, 0);
            }
        }

        // epilogue: O^T col=q (lane&15), row d = dsub*16+lgrp*4+r
#pragma unroll
        for (int qm = 0; qm < 4; ++qm) {
            int q = qbase + qm * 16 + lrow;
            if (q >= L) continue;
            float inv = 1.f / lrun[qm];
            unsigned short* dst = ctxb + (size_t)(s0 + q) * 256 + h * 32;
#pragma unroll
            for (int dsub = 0; dsub < 2; ++dsub) {
#pragma unroll
                for (int rp = 0; rp < 4; rp += 2) {
                    *(unsigned int*)&dst[dsub * 16 + lgrp * 4 + rp] =
                        pk2(acc[qm][dsub][rp] * inv, acc[qm][dsub][rp + 1] * inv);
                }
            }
        }
    }
}

// ---------------- per-graph LN stats (graph mode) --------------------------
__global__ __launch_bounds__(256) void k_stats(
    const float* __restrict__ hbuf, const int* __restrict__ starts,
    const int* __restrict__ counts, float* __restrict__ stats) {
    int g = blockIdx.x;
    int s0 = starts[g];
    int cnt = counts[g];
    size_t total4 = (size_t)cnt * (D_EMB / 4);
    const float4* p = (const float4*)(hbuf + (size_t)s0 * D_EMB);

    float sum = 0.f, sq = 0.f;
    for (size_t i = threadIdx.x; i < total4; i += 256) {
        float4 v = p[i];
        sum += v.x + v.y + v.z + v.w;
        sq += v.x * v.x + v.y * v.y + v.z * v.z + v.w * v.w;
    }
#pragma unroll
    for (int o = 32; o > 0; o >>= 1) {
        sum += __shfl_down(sum, o);
        sq += __shfl_down(sq, o);
    }
    __shared__ float ssum[4], ssq[4];
    int wid = threadIdx.x >> 6, lane = threadIdx.x & 63;
    if (lane == 0) { ssum[wid] = sum; ssq[wid] = sq; }
    __syncthreads();
    if (threadIdx.x == 0) {
        float S = 0.f, Q = 0.f;
#pragma unroll
        for (int w = 0; w < 4; ++w) { S += ssum[w]; Q += ssq[w]; }
        float norm = (float)cnt * (float)D_EMB;
        float mean = S / norm;
        float var = Q / norm - mean * mean;
        stats[g * 2] = mean;
        stats[g * 2 + 1] = rsqrtf(var + 1e-5f);
    }
}

// ---------------- LN apply + exact GELU, in place --------------------------
__global__ void k_ln_gelu(float* __restrict__ h, const int* __restrict__ batch,
                          const float* __restrict__ stats, const float* __restrict__ lw,
                          const float* __restrict__ lb, int n) {
    int idx = blockIdx.x * blockDim.x + threadIdx.x;
    if (idx >= n * (D_EMB / 4)) return;
    int row = idx >> 6;
    int c4 = idx & 63;
    int g = batch[row];
    float mean = stats[2 * g], inv = stats[2 * g + 1];
    float4 v = *(float4*)&h[(size_t)idx * 4];
    float4 wv = *(const float4*)&lw[c4 * 4];
    float4 bv = *(const float4*)&lb[c4 * 4];
    float y;
    y = (v.x - mean) * inv * wv.x + bv.x; v.x = 0.5f * y * (1.f + erff(y * 0.70710678118f));
    y = (v.y - mean) * inv * wv.y + bv.y; v.y = 0.5f * y * (1.f + erff(y * 0.70710678118f));
    y = (v.z - mean) * inv * wv.z + bv.z; v.z = 0.5f * y * (1.f + erff(y * 0.70710678118f));
    y = (v.w - mean) * inv * wv.w + bv.w; v.w = 0.5f * y * (1.f + erff(y * 0.70710678118f));
    *(float4*)&h[(size_t)idx * 4] = v;
}

// ---------------- launch ----------------------------------------------------
extern "C" void kernel_launch(void* const* d_in, const int* in_sizes, int n_in,
                              void* d_out, int out_size, void* d_ws, size_t ws_size,
                              hipStream_t stream) {
    const float* x     = (const float*)d_in[0];
    const int*   batch = (const int*)d_in[1];
    const float* in_w  = (const float*)d_in[2];
    const float* in_b  = (const float*)d_in[3];
    const float* out_w = (const float*)d_in[4];
    const float* out_b = (const float*)d_in[5];
    const float* ln_w  = (const float*)d_in[6];
    const float* ln_b  = (const float*)d_in[7];
    int N = in_sizes[1];
    float* out = (float*)d_out;

    char* ws = (char*)d_ws;
    int*   starts = (int*)ws;                         // 64
    int*   counts = starts + 64;                      // 64
    float* stats  = (float*)(ws + 512);               // 128 floats
    unsigned short* xb   = (unsigned short*)(ws + 1024);
    unsigned short* wb1  = xb + (size_t)N * 256;
    unsigned short* wb2  = wb1 + 768 * 256;
    unsigned short* Qb   = wb2 + 256 * 256;
    unsigned short* Kb   = Qb + (size_t)N * 256;
    unsigned short* Vb   = Kb + (size_t)N * 256;
    unsigned short* ctxb = Vb + (size_t)N * 256;

    k_starts<<<(N + 255) / 256, 256, 0, stream>>>(batch, N, starts);
    k_counts<<<1, 64, 0, stream>>>(starts, N, counts);

    int n4x = N * 64;
    k_f2bf4<<<(n4x + 255) / 256, 256, 0, stream>>>(x, xb, n4x);
    k_f2bf4<<<(768 * 64 + 255) / 256, 256, 0, stream>>>(in_w, wb1, 768 * 64);
    k_f2bf4<<<(256 * 64 + 255) / 256, 256, 0, stream>>>(out_w, wb2, 256 * 64);

    dim3 g1((N + 127) / 128, 6);
    k_gemm<1><<<g1, 256, 0, stream>>>(xb, wb1, in_b, nullptr, nullptr,
                                      Qb, Kb, Vb, N, 768);

    k_attn3<<<dim3(NG, NHEAD), 256, 0, stream>>>(Qb, Kb, Vb, starts, counts, ctxb);

    dim3 g3((N + 127) / 128, 2);
    k_gemm<0><<<g3, 256, 0, stream>>>(ctxb, wb2, out_b, x, out,
                                      nullptr, nullptr, nullptr, N, 256);

    k_stats<<<NG, 256, 0, stream>>>(out, starts, counts, stats);

    int nv4 = N * (D_EMB / 4);
    k_ln_gelu<<<(nv4 + 255) / 256, 256, 0, stream>>>(out, batch, stats, ln_w, ln_b, N);
}

// Round 7
// 185.434 us; speedup vs baseline: 1.2844x; 1.2229x over previous
//
#include <hip/hip_runtime.h>
#include <hip/hip_bf16.h>
#include <math.h>

#define D_EMB 256
#define NHEAD 8
#define HD 32
#define NG 64
// 1/sqrt(32) * log2(e): softmax runs in exp2 domain, scale folded into Q
#define QSC 0.25503486f

typedef __attribute__((ext_vector_type(8))) short short8b;   // 8 bf16 (4 VGPR)
typedef __attribute__((ext_vector_type(4))) float f32x4;

__device__ __forceinline__ unsigned int pk2(float a, float b) {
    union { __hip_bfloat162 t; unsigned int u; } r;
    r.t = __float22bfloat162_rn(make_float2(a, b));
    return r.u;
}

// pack two f32x4 score vectors into one bf16x8 fragment
__device__ __forceinline__ short8b pack2v(f32x4 a, f32x4 b) {
    union { unsigned int u[4]; short8b s; } r;
    r.u[0] = pk2(a[0], a[1]);
    r.u[1] = pk2(a[2], a[3]);
    r.u[2] = pk2(b[0], b[1]);
    r.u[3] = pk2(b[2], b[3]);
    return r.s;
}

// ---------------- meta: starts / counts from sorted batch ----------------
__global__ void k_starts(const int* __restrict__ batch, int n, int* __restrict__ starts) {
    int i = blockIdx.x * blockDim.x + threadIdx.x;
    if (i >= n) return;
    int b = batch[i];
    if (i == 0 || batch[i - 1] != b) starts[b] = i;
}

__global__ void k_counts(const int* __restrict__ starts, int n, int* __restrict__ counts) {
    int g = threadIdx.x;
    if (g < NG) {
        int s = starts[g];
        int e = (g == NG - 1) ? n : starts[g + 1];
        counts[g] = e - s;
    }
}

// ---------------- fp32 -> bf16 bulk convert --------------------------------
__global__ void k_f2bf4(const float* __restrict__ src, unsigned short* __restrict__ dst, int n4) {
    int i = blockIdx.x * blockDim.x + threadIdx.x;
    if (i >= n4) return;
    float4 v = ((const float4*)src)[i];
    uint2 o;
    o.x = pk2(v.x, v.y);
    o.y = pk2(v.z, v.w);
    ((uint2*)dst)[i] = o;
}

// ---------------- bf16 LDS-staged MFMA GEMM --------------------------------
// C = A(Mx256) * W(Nx256)^T.  128x128 tile, 4 waves (2x2), BK=64.
// MODE 0: fp32 out + bias + resid.  MODE 1: bf16 Q(pre-scaled)/K/V split.
#define GLSW 72  // LDS row stride in ushort (144 B)

template<int MODE>
__global__ __launch_bounds__(256) void k_gemm(
    const unsigned short* __restrict__ A, const unsigned short* __restrict__ W,
    const float* __restrict__ bias, const float* __restrict__ resid,
    float* __restrict__ Cf, unsigned short* __restrict__ Qb,
    unsigned short* __restrict__ Kb, unsigned short* __restrict__ Vb,
    int M, int Ncols) {
    __shared__ __align__(16) unsigned short Al[128][GLSW];
    __shared__ __align__(16) unsigned short Bl[128][GLSW];

    int tid = threadIdx.x;
    int wave = tid >> 6, lane = tid & 63;
    int lrow = lane & 15, lgrp = lane >> 4;
    int wr = wave >> 1, wc = wave & 1;
    int row0 = blockIdx.x * 128, col0 = blockIdx.y * 128;

    f32x4 acc[4][4];
#pragma unroll
    for (int i = 0; i < 4; ++i)
#pragma unroll
        for (int j = 0; j < 4; ++j) acc[i][j] = (f32x4){0.f, 0.f, 0.f, 0.f};

    for (int k0 = 0; k0 < 256; k0 += 64) {
#pragma unroll
        for (int p = 0; p < 4; ++p) {
            int idx = tid + p * 256;
            int r = idx >> 3, c = (idx & 7) * 8;
            int ar = row0 + r; if (ar >= M) ar = M - 1;
            *(short8b*)&Al[r][c] = *(const short8b*)&A[(size_t)ar * 256 + k0 + c];
            *(short8b*)&Bl[r][c] = *(const short8b*)&W[(size_t)(col0 + r) * 256 + k0 + c];
        }
        __syncthreads();
#pragma unroll
        for (int half = 0; half < 2; ++half) {
            short8b af[4], bf[4];
#pragma unroll
            for (int mi = 0; mi < 4; ++mi)
                af[mi] = *(const short8b*)&Al[wr * 64 + mi * 16 + lrow][half * 32 + lgrp * 8];
#pragma unroll
            for (int ni = 0; ni < 4; ++ni)
                bf[ni] = *(const short8b*)&Bl[wc * 64 + ni * 16 + lrow][half * 32 + lgrp * 8];
#pragma unroll
            for (int mi = 0; mi < 4; ++mi)
#pragma unroll
                for (int ni = 0; ni < 4; ++ni)
                    acc[mi][ni] = __builtin_amdgcn_mfma_f32_16x16x32_bf16(
                        af[mi], bf[ni], acc[mi][ni], 0, 0, 0);
        }
        __syncthreads();
    }

    if (MODE == 0) {
#pragma unroll
        for (int ni = 0; ni < 4; ++ni) {
            int col = col0 + wc * 64 + ni * 16 + lrow;
            float bv = bias[col];
#pragma unroll
            for (int mi = 0; mi < 4; ++mi) {
                int rowb = row0 + wr * 64 + mi * 16 + lgrp * 4;
#pragma unroll
                for (int r = 0; r < 4; ++r) {
                    int row = rowb + r;
                    if (row < M) {
                        float v = acc[mi][ni][r] + bv;
                        v += resid[(size_t)row * Ncols + col];
                        Cf[(size_t)row * Ncols + col] = v;
                    }
                }
            }
        }
    } else {
        int sel = blockIdx.y >> 1;  // 0:Q 1:K 2:V
        unsigned short* dst = sel == 0 ? Qb : (sel == 1 ? Kb : Vb);
        float qsc = sel == 0 ? QSC : 1.f;
#pragma unroll
        for (int ni = 0; ni < 4; ++ni) {
            int colg = col0 + wc * 64 + ni * 16 + lrow;
            int col = colg & 255;
            float bv = bias[colg];
#pragma unroll
            for (int mi = 0; mi < 4; ++mi) {
                int rowb = row0 + wr * 64 + mi * 16 + lgrp * 4;
#pragma unroll
                for (int r = 0; r < 4; ++r) {
                    int row = rowb + r;
                    if (row < M) {
                        union { __hip_bfloat16 b; unsigned short u; } cv;
                        cv.b = __float2bfloat16((acc[mi][ni][r] + bv) * qsc);
                        dst[(size_t)row * 256 + col] = cv.u;
                    }
                }
            }
        }
    }
}

// ---------------- MFMA attention v4 ----------------------------------------
// grid = (graph, head, 4 q-chunks of 128); block = 4 waves x 32 q.
// 64-key tiles: K + V^T in small LDS (9.5 KB), global->reg prefetch of t+1
// issued before computing t; 2 barriers/tile. Softmax in exp2 domain with
// pre-scaled Q, tail-only masking, exact defer-max, in-place on MFMA vectors.
__global__ __launch_bounds__(256) void k_attn4(
    const unsigned short* __restrict__ Qb, const unsigned short* __restrict__ Kb,
    const unsigned short* __restrict__ Vb, const int* __restrict__ starts,
    const int* __restrict__ counts, unsigned short* __restrict__ ctxb) {
    int g = blockIdx.x, h = blockIdx.y, chunk = blockIdx.z;
    int L = counts[g], s0 = starts[g];
    if (chunk * 128 >= L) return;

    __shared__ __align__(16) unsigned short Klds[64][40];  // 5120 B
    __shared__ __align__(16) unsigned short Vt[32][72];    // 4608 B

    int tid = threadIdx.x;
    int wave = tid >> 6, lane = tid & 63;
    int lrow = lane & 15, lgrp = lane >> 4;
    int qbase = chunk * 128 + wave * 32;

    // Q fragments (B-operand: col q = lane&15, k(d) = lgrp*8+j), pre-scaled
    short8b qf[2];
#pragma unroll
    for (int qm = 0; qm < 2; ++qm) {
        int qr = qbase + qm * 16 + lrow;
        if (qr >= L) qr = L - 1;  // clamp; output discarded
        qf[qm] = *(const short8b*)&Qb[(size_t)(s0 + qr) * 256 + h * 32 + lgrp * 8];
    }

    // staging indices: K one short8b/thread; V two ushort4/thread (transposed)
    int skey = tid >> 2, skc = (tid & 3) * 8;
    int vkey = tid >> 3, vd4 = (tid & 7) * 4;
    int sig = ((vkey >> 2) & 3) * 8 + (vkey >> 4) * 4 + (vkey & 3);  // vkey in 0..31
    int vcol0 = sig, vcol1 = 32 + sig;                               // key and key+32

    // prologue: stage tile 0
    {
        int kr = skey < L ? skey : L - 1;
        *(short8b*)&Klds[skey][skc] = *(const short8b*)&Kb[(size_t)(s0 + kr) * 256 + h * 32 + skc];
        int vr0 = vkey < L ? vkey : L - 1;
        int vr1 = (vkey + 32) < L ? (vkey + 32) : L - 1;
        ushort4 v0 = *(const ushort4*)&Vb[(size_t)(s0 + vr0) * 256 + h * 32 + vd4];
        ushort4 v1 = *(const ushort4*)&Vb[(size_t)(s0 + vr1) * 256 + h * 32 + vd4];
        Vt[vd4 + 0][vcol0] = v0.x; Vt[vd4 + 1][vcol0] = v0.y;
        Vt[vd4 + 2][vcol0] = v0.z; Vt[vd4 + 3][vcol0] = v0.w;
        Vt[vd4 + 0][vcol1] = v1.x; Vt[vd4 + 1][vcol1] = v1.y;
        Vt[vd4 + 2][vcol1] = v1.z; Vt[vd4 + 3][vcol1] = v1.w;
    }

    float mrun[2] = {-INFINITY, -INFINITY};
    float lrun[2] = {0.f, 0.f};
    f32x4 acc[2][2];
#pragma unroll
    for (int a = 0; a < 2; ++a) {
        acc[a][0] = (f32x4){0.f, 0.f, 0.f, 0.f};
        acc[a][1] = (f32x4){0.f, 0.f, 0.f, 0.f};
    }

    int nkt = (L + 63) >> 6;
    for (int t = 0; t < nkt; ++t) {
        int kt = t * 64;
        __syncthreads();  // LDS tile t ready

        short8b kf[4];
#pragma unroll
        for (int kn = 0; kn < 4; ++kn)
            kf[kn] = *(const short8b*)&Klds[kn * 16 + lrow][lgrp * 8];
        short8b vf[2][2];
#pragma unroll
        for (int dsub = 0; dsub < 2; ++dsub)
#pragma unroll
            for (int kh = 0; kh < 2; ++kh)
                vf[dsub][kh] = *(const short8b*)&Vt[dsub * 16 + lrow][kh * 32 + lgrp * 8];

        // prefetch tile t+1 global -> regs (latency hidden under compute)
        bool more = (t + 1) < nkt;
        short8b kreg;
        ushort4 vreg0, vreg1;
        if (more) {
            int ktn = kt + 64;
            int kr = (ktn + skey) < L ? (ktn + skey) : L - 1;
            kreg = *(const short8b*)&Kb[(size_t)(s0 + kr) * 256 + h * 32 + skc];
            int vr0 = (ktn + vkey) < L ? (ktn + vkey) : L - 1;
            int vr1 = (ktn + vkey + 32) < L ? (ktn + vkey + 32) : L - 1;
            vreg0 = *(const ushort4*)&Vb[(size_t)(s0 + vr0) * 256 + h * 32 + vd4];
            vreg1 = *(const ushort4*)&Vb[(size_t)(s0 + vr1) * 256 + h * 32 + vd4];
        }

        bool tail = (kt + 64 > L);
        short8b pf[2][2];
#pragma unroll
        for (int qm = 0; qm < 2; ++qm) {
            f32x4 s[4];
#pragma unroll
            for (int kn = 0; kn < 4; ++kn)
                s[kn] = __builtin_amdgcn_mfma_f32_16x16x32_bf16(
                    kf[kn], qf[qm], (f32x4){0.f, 0.f, 0.f, 0.f}, 0, 0, 0);
            if (tail) {
#pragma unroll
                for (int kn = 0; kn < 4; ++kn)
#pragma unroll
                    for (int r = 0; r < 4; ++r) {
                        int key = kt + kn * 16 + lgrp * 4 + r;
                        if (key >= L) s[kn][r] = -INFINITY;
                    }
            }
            float mx = s[0][0];
#pragma unroll
            for (int kn = 0; kn < 4; ++kn)
#pragma unroll
                for (int r = 0; r < 4; ++r) mx = fmaxf(mx, s[kn][r]);
            mx = fmaxf(mx, __shfl_xor(mx, 16));
            mx = fmaxf(mx, __shfl_xor(mx, 32));
            float mq = mrun[qm];
            if (!__all(mx <= mq)) {  // exact skip: if no lane grew, fsc==1
                float mnew = fmaxf(mq, mx);
                float fs = exp2f(mq - mnew);
                lrun[qm] *= fs;
#pragma unroll
                for (int e = 0; e < 4; ++e) { acc[qm][0][e] *= fs; acc[qm][1][e] *= fs; }
                mrun[qm] = mnew;
                mq = mnew;
            }
            float ps = 0.f;
#pragma unroll
            for (int kn = 0; kn < 4; ++kn)
#pragma unroll
                for (int r = 0; r < 4; ++r) {
                    float pv = exp2f(s[kn][r] - mq);
                    s[kn][r] = pv;
                    ps += pv;
                }
            ps += __shfl_xor(ps, 16);
            ps += __shfl_xor(ps, 32);
            lrun[qm] += ps;
            pf[qm][0] = pack2v(s[0], s[1]);
            pf[qm][1] = pack2v(s[2], s[3]);
        }

        // PV: O^T += V^T P^T (sigma-permuted key order on both sides)
#pragma unroll
        for (int qm = 0; qm < 2; ++qm)
#pragma unroll
            for (int dsub = 0; dsub < 2; ++dsub) {
                acc[qm][dsub] = __builtin_amdgcn_mfma_f32_16x16x32_bf16(
                    vf[dsub][0], pf[qm][0], acc[qm][dsub], 0, 0, 0);
                acc[qm][dsub] = __builtin_amdgcn_mfma_f32_16x16x32_bf16(
                    vf[dsub][1], pf[qm][1], acc[qm][dsub], 0, 0, 0);
            }

        __syncthreads();  // all waves done reading tile t
        if (more) {
            *(short8b*)&Klds[skey][skc] = kreg;
            Vt[vd4 + 0][vcol0] = vreg0.x; Vt[vd4 + 1][vcol0] = vreg0.y;
            Vt[vd4 + 2][vcol0] = vreg0.z; Vt[vd4 + 3][vcol0] = vreg0.w;
            Vt[vd4 + 0][vcol1] = vreg1.x; Vt[vd4 + 1][vcol1] = vreg1.y;
            Vt[vd4 + 2][vcol1] = vreg1.z; Vt[vd4 + 3][vcol1] = vreg1.w;
        }
    }

    // epilogue: O^T col=q (lane&15), row d = dsub*16+lgrp*4+r; bf16 stores
#pragma unroll
    for (int qm = 0; qm < 2; ++qm) {
        int q = qbase + qm * 16 + lrow;
        if (q >= L) continue;
        float inv = 1.f / lrun[qm];
        unsigned short* dst = ctxb + (size_t)(s0 + q) * 256 + h * 32;
#pragma unroll
        for (int dsub = 0; dsub < 2; ++dsub) {
#pragma unroll
            for (int rp = 0; rp < 4; rp += 2) {
                *(unsigned int*)&dst[dsub * 16 + lgrp * 4 + rp] =
                    pk2(acc[qm][dsub][rp] * inv, acc[qm][dsub][rp + 1] * inv);
            }
        }
    }
}

// ---------------- per-graph LN stats: 4 partial blocks per graph -----------
__global__ __launch_bounds__(256) void k_stats_part(
    const float* __restrict__ hbuf, const int* __restrict__ starts,
    const int* __restrict__ counts, float* __restrict__ part) {
    int g = blockIdx.x, qq = blockIdx.y;
    int s0 = starts[g], cnt = counts[g];
    int cq = (cnt + 3) >> 2;
    int r0 = qq * cq;
    int r1 = min(cnt, r0 + cq);

    float sum = 0.f, sq = 0.f;
    if (r0 < r1) {
        const float4* p = (const float4*)(hbuf + (size_t)(s0 + r0) * D_EMB);
        size_t n4 = (size_t)(r1 - r0) * (D_EMB / 4);
        for (size_t i = threadIdx.x; i < n4; i += 256) {
            float4 v = p[i];
            sum += v.x + v.y + v.z + v.w;
            sq += v.x * v.x + v.y * v.y + v.z * v.z + v.w * v.w;
        }
    }
#pragma unroll
    for (int o = 32; o > 0; o >>= 1) {
        sum += __shfl_down(sum, o);
        sq += __shfl_down(sq, o);
    }
    __shared__ float ssum[4], ssq[4];
    int wid = threadIdx.x >> 6, lane = threadIdx.x & 63;
    if (lane == 0) { ssum[wid] = sum; ssq[wid] = sq; }
    __syncthreads();
    if (threadIdx.x == 0) {
        float S = 0.f, Q = 0.f;
#pragma unroll
        for (int w = 0; w < 4; ++w) { S += ssum[w]; Q += ssq[w]; }
        part[(g * 4 + qq) * 2] = S;
        part[(g * 4 + qq) * 2 + 1] = Q;
    }
}

__global__ void k_stats_final(const float* __restrict__ part,
                              const int* __restrict__ counts,
                              float* __restrict__ stats) {
    int g = threadIdx.x;
    if (g >= NG) return;
    float S = 0.f, Q = 0.f;
#pragma unroll
    for (int i = 0; i < 4; ++i) {
        S += part[(g * 4 + i) * 2];
        Q += part[(g * 4 + i) * 2 + 1];
    }
    float norm = (float)counts[g] * (float)D_EMB;
    float mean = S / norm;
    float var = Q / norm - mean * mean;
    stats[2 * g] = mean;
    stats[2 * g + 1] = rsqrtf(var + 1e-5f);
}

// ---------------- LN apply + exact GELU, in place --------------------------
__global__ void k_ln_gelu(float* __restrict__ h, const int* __restrict__ batch,
                          const float* __restrict__ stats, const float* __restrict__ lw,
                          const float* __restrict__ lb, int n) {
    int idx = blockIdx.x * blockDim.x + threadIdx.x;
    if (idx >= n * (D_EMB / 4)) return;
    int row = idx >> 6;
    int c4 = idx & 63;
    int g = batch[row];
    float mean = stats[2 * g], inv = stats[2 * g + 1];
    float4 v = *(float4*)&h[(size_t)idx * 4];
    float4 wv = *(const float4*)&lw[c4 * 4];
    float4 bv = *(const float4*)&lb[c4 * 4];
    float y;
    y = (v.x - mean) * inv * wv.x + bv.x; v.x = 0.5f * y * (1.f + erff(y * 0.70710678118f));
    y = (v.y - mean) * inv * wv.y + bv.y; v.y = 0.5f * y * (1.f + erff(y * 0.70710678118f));
    y = (v.z - mean) * inv * wv.z + bv.z; v.z = 0.5f * y * (1.f + erff(y * 0.70710678118f));
    y = (v.w - mean) * inv * wv.w + bv.w; v.w = 0.5f * y * (1.f + erff(y * 0.70710678118f));
    *(float4*)&h[(size_t)idx * 4] = v;
}

// ---------------- launch ----------------------------------------------------
extern "C" void kernel_launch(void* const* d_in, const int* in_sizes, int n_in,
                              void* d_out, int out_size, void* d_ws, size_t ws_size,
                              hipStream_t stream) {
    const float* x     = (const float*)d_in[0];
    const int*   batch = (const int*)d_in[1];
    const float* in_w  = (const float*)d_in[2];
    const float* in_b  = (const float*)d_in[3];
    const float* out_w = (const float*)d_in[4];
    const float* out_b = (const float*)d_in[5];
    const float* ln_w  = (const float*)d_in[6];
    const float* ln_b  = (const float*)d_in[7];
    int N = in_sizes[1];
    float* out = (float*)d_out;

    char* ws = (char*)d_ws;
    int*   starts = (int*)ws;                         // 64 ints
    int*   counts = starts + 64;                      // 64 ints
    float* stats  = (float*)(ws + 512);               // 128 floats
    float* part   = (float*)(ws + 1024);              // 512 floats
    unsigned short* xb   = (unsigned short*)(ws + 3072);
    unsigned short* wb1  = xb + (size_t)N * 256;
    unsigned short* wb2  = wb1 + 768 * 256;
    unsigned short* Qb   = wb2 + 256 * 256;
    unsigned short* Kb   = Qb + (size_t)N * 256;
    unsigned short* Vb   = Kb + (size_t)N * 256;
    unsigned short* ctxb = Vb + (size_t)N * 256;

    k_starts<<<(N + 255) / 256, 256, 0, stream>>>(batch, N, starts);
    k_counts<<<1, 64, 0, stream>>>(starts, N, counts);

    int n4x = N * 64;
    k_f2bf4<<<(n4x + 255) / 256, 256, 0, stream>>>(x, xb, n4x);
    k_f2bf4<<<(768 * 64 + 255) / 256, 256, 0, stream>>>(in_w, wb1, 768 * 64);
    k_f2bf4<<<(256 * 64 + 255) / 256, 256, 0, stream>>>(out_w, wb2, 256 * 64);

    dim3 g1((N + 127) / 128, 6);
    k_gemm<1><<<g1, 256, 0, stream>>>(xb, wb1, in_b, nullptr, nullptr,
                                      Qb, Kb, Vb, N, 768);

    k_attn4<<<dim3(NG, NHEAD, 4), 256, 0, stream>>>(Qb, Kb, Vb, starts, counts, ctxb);

    dim3 g3((N + 127) / 128, 2);
    k_gemm<0><<<g3, 256, 0, stream>>>(ctxb, wb2, out_b, x, out,
                                      nullptr, nullptr, nullptr, N, 256);

    k_stats_part<<<dim3(NG, 4), 256, 0, stream>>>(out, starts, counts, part);
    k_stats_final<<<1, 64, 0, stream>>>(part, counts, stats);

    int nv4 = N * (D_EMB / 4);
    k_ln_gelu<<<(nv4 + 255) / 256, 256, 0, stream>>>(out, batch, stats, ln_w, ln_b, N);
}

// Round 8
// 182.232 us; speedup vs baseline: 1.3070x; 1.0176x over previous
//
#include <hip/hip_runtime.h>
#include <hip/hip_bf16.h>
#include <math.h>

#define D_EMB 256
#define NHEAD 8
#define HD 32
#define NG 64
// 1/sqrt(32) * log2(e): softmax runs in exp2 domain, scale folded into Q
#define QSC 0.25503486f

typedef __attribute__((ext_vector_type(8))) short short8b;   // 8 bf16 (4 VGPR)
typedef __attribute__((ext_vector_type(4))) float f32x4;

__device__ __forceinline__ unsigned int pk2(float a, float b) {
    union { __hip_bfloat162 t; unsigned int u; } r;
    r.t = __float22bfloat162_rn(make_float2(a, b));
    return r.u;
}

// pack two f32x4 score vectors into one bf16x8 fragment
__device__ __forceinline__ short8b pack2v(f32x4 a, f32x4 b) {
    union { unsigned int u[4]; short8b s; } r;
    r.u[0] = pk2(a[0], a[1]);
    r.u[1] = pk2(a[2], a[3]);
    r.u[2] = pk2(b[0], b[1]);
    r.u[3] = pk2(b[2], b[3]);
    return r.s;
}

// ---------------- meta: starts / counts from sorted batch ----------------
__global__ void k_starts(const int* __restrict__ batch, int n, int* __restrict__ starts) {
    int i = blockIdx.x * blockDim.x + threadIdx.x;
    if (i >= n) return;
    int b = batch[i];
    if (i == 0 || batch[i - 1] != b) starts[b] = i;
}

__global__ void k_counts(const int* __restrict__ starts, int n, int* __restrict__ counts) {
    int g = threadIdx.x;
    if (g < NG) {
        int s = starts[g];
        int e = (g == NG - 1) ? n : starts[g + 1];
        counts[g] = e - s;
    }
}

// ---------------- fp32 -> bf16 bulk convert --------------------------------
__global__ void k_f2bf4(const float* __restrict__ src, unsigned short* __restrict__ dst, int n4) {
    int i = blockIdx.x * blockDim.x + threadIdx.x;
    if (i >= n4) return;
    float4 v = ((const float4*)src)[i];
    uint2 o;
    o.x = pk2(v.x, v.y);
    o.y = pk2(v.z, v.w);
    ((uint2*)dst)[i] = o;
}

// ---------------- bf16 LDS-staged MFMA GEMM --------------------------------
// C = A(Mx256) * W(Nx256)^T.  128x128 tile, 4 waves (2x2), BK=64.
// MODE 0: fp32 out + bias + resid.  MODE 1: bf16 Q(pre-scaled)/K/V split.
#define GLSW 72  // LDS row stride in ushort (144 B)

template<int MODE>
__global__ __launch_bounds__(256) void k_gemm(
    const unsigned short* __restrict__ A, const unsigned short* __restrict__ W,
    const float* __restrict__ bias, const float* __restrict__ resid,
    float* __restrict__ Cf, unsigned short* __restrict__ Qb,
    unsigned short* __restrict__ Kb, unsigned short* __restrict__ Vb,
    int M, int Ncols) {
    __shared__ __align__(16) unsigned short Al[128][GLSW];
    __shared__ __align__(16) unsigned short Bl[128][GLSW];

    int tid = threadIdx.x;
    int wave = tid >> 6, lane = tid & 63;
    int lrow = lane & 15, lgrp = lane >> 4;
    int wr = wave >> 1, wc = wave & 1;
    int row0 = blockIdx.x * 128, col0 = blockIdx.y * 128;

    f32x4 acc[4][4];
#pragma unroll
    for (int i = 0; i < 4; ++i)
#pragma unroll
        for (int j = 0; j < 4; ++j) acc[i][j] = (f32x4){0.f, 0.f, 0.f, 0.f};

    for (int k0 = 0; k0 < 256; k0 += 64) {
#pragma unroll
        for (int p = 0; p < 4; ++p) {
            int idx = tid + p * 256;
            int r = idx >> 3, c = (idx & 7) * 8;
            int ar = row0 + r; if (ar >= M) ar = M - 1;
            *(short8b*)&Al[r][c] = *(const short8b*)&A[(size_t)ar * 256 + k0 + c];
            *(short8b*)&Bl[r][c] = *(const short8b*)&W[(size_t)(col0 + r) * 256 + k0 + c];
        }
        __syncthreads();
#pragma unroll
        for (int half = 0; half < 2; ++half) {
            short8b af[4], bf[4];
#pragma unroll
            for (int mi = 0; mi < 4; ++mi)
                af[mi] = *(const short8b*)&Al[wr * 64 + mi * 16 + lrow][half * 32 + lgrp * 8];
#pragma unroll
            for (int ni = 0; ni < 4; ++ni)
                bf[ni] = *(const short8b*)&Bl[wc * 64 + ni * 16 + lrow][half * 32 + lgrp * 8];
#pragma unroll
            for (int mi = 0; mi < 4; ++mi)
#pragma unroll
                for (int ni = 0; ni < 4; ++ni)
                    acc[mi][ni] = __builtin_amdgcn_mfma_f32_16x16x32_bf16(
                        af[mi], bf[ni], acc[mi][ni], 0, 0, 0);
        }
        __syncthreads();
    }

    if (MODE == 0) {
#pragma unroll
        for (int ni = 0; ni < 4; ++ni) {
            int col = col0 + wc * 64 + ni * 16 + lrow;
            float bv = bias[col];
#pragma unroll
            for (int mi = 0; mi < 4; ++mi) {
                int rowb = row0 + wr * 64 + mi * 16 + lgrp * 4;
#pragma unroll
                for (int r = 0; r < 4; ++r) {
                    int row = rowb + r;
                    if (row < M) {
                        float v = acc[mi][ni][r] + bv;
                        v += resid[(size_t)row * Ncols + col];
                        Cf[(size_t)row * Ncols + col] = v;
                    }
                }
            }
        }
    } else {
        int sel = blockIdx.y >> 1;  // 0:Q 1:K 2:V
        unsigned short* dst = sel == 0 ? Qb : (sel == 1 ? Kb : Vb);
        float qsc = sel == 0 ? QSC : 1.f;
#pragma unroll
        for (int ni = 0; ni < 4; ++ni) {
            int colg = col0 + wc * 64 + ni * 16 + lrow;
            int col = colg & 255;
            float bv = bias[colg];
#pragma unroll
            for (int mi = 0; mi < 4; ++mi) {
                int rowb = row0 + wr * 64 + mi * 16 + lgrp * 4;
#pragma unroll
                for (int r = 0; r < 4; ++r) {
                    int row = rowb + r;
                    if (row < M) {
                        union { __hip_bfloat16 b; unsigned short u; } cv;
                        cv.b = __float2bfloat16((acc[mi][ni][r] + bv) * qsc);
                        dst[(size_t)row * 256 + col] = cv.u;
                    }
                }
            }
        }
    }
}

// ---------------- MFMA attention v5 ----------------------------------------
// grid = (graph, head, 4 q-chunks of 128); block = 4 waves x 32 q.
// 64-key tiles, K + V^T in small LDS, global->reg prefetch of t+1.
// STATIC-MAX softmax (exact: max subtraction cancels in softmax; fp32 can't
// overflow for clamped scores): no fmax tree, no per-tile shuffles, no
// rescale, no branches -- pure exp2+add+pack between the MFMA clusters.
// Row-sum reduce deferred to the epilogue (2 shuffles per q-tile total).
__global__ __launch_bounds__(256) void k_attn5(
    const unsigned short* __restrict__ Qb, const unsigned short* __restrict__ Kb,
    const unsigned short* __restrict__ Vb, const int* __restrict__ starts,
    const int* __restrict__ counts, unsigned short* __restrict__ ctxb) {
    int g = blockIdx.x, h = blockIdx.y, chunk = blockIdx.z;
    int L = counts[g], s0 = starts[g];
    if (chunk * 128 >= L) return;

    __shared__ __align__(16) unsigned short Klds[64][40];  // 5120 B
    __shared__ __align__(16) unsigned short Vt[32][72];    // 4608 B

    int tid = threadIdx.x;
    int wave = tid >> 6, lane = tid & 63;
    int lrow = lane & 15, lgrp = lane >> 4;
    int qbase = chunk * 128 + wave * 32;

    // Q fragments (B-operand: col q = lane&15, k(d) = lgrp*8+j), pre-scaled
    short8b qf[2];
#pragma unroll
    for (int qm = 0; qm < 2; ++qm) {
        int qr = qbase + qm * 16 + lrow;
        if (qr >= L) qr = L - 1;  // clamp; output discarded
        qf[qm] = *(const short8b*)&Qb[(size_t)(s0 + qr) * 256 + h * 32 + lgrp * 8];
    }

    // staging indices: K one short8b/thread; V two ushort4/thread (transposed)
    int skey = tid >> 2, skc = (tid & 3) * 8;
    int vkey = tid >> 3, vd4 = (tid & 7) * 4;
    int sig = ((vkey >> 2) & 3) * 8 + (vkey >> 4) * 4 + (vkey & 3);  // vkey in 0..31
    int vcol0 = sig, vcol1 = 32 + sig;                               // key and key+32

    // prologue: stage tile 0
    {
        int kr = skey < L ? skey : L - 1;
        *(short8b*)&Klds[skey][skc] = *(const short8b*)&Kb[(size_t)(s0 + kr) * 256 + h * 32 + skc];
        int vr0 = vkey < L ? vkey : L - 1;
        int vr1 = (vkey + 32) < L ? (vkey + 32) : L - 1;
        ushort4 v0 = *(const ushort4*)&Vb[(size_t)(s0 + vr0) * 256 + h * 32 + vd4];
        ushort4 v1 = *(const ushort4*)&Vb[(size_t)(s0 + vr1) * 256 + h * 32 + vd4];
        Vt[vd4 + 0][vcol0] = v0.x; Vt[vd4 + 1][vcol0] = v0.y;
        Vt[vd4 + 2][vcol0] = v0.z; Vt[vd4 + 3][vcol0] = v0.w;
        Vt[vd4 + 0][vcol1] = v1.x; Vt[vd4 + 1][vcol1] = v1.y;
        Vt[vd4 + 2][vcol1] = v1.z; Vt[vd4 + 3][vcol1] = v1.w;
    }

    float lrun[2] = {0.f, 0.f};  // per-lane partial sums; reduced in epilogue
    f32x4 acc[2][2];
#pragma unroll
    for (int a = 0; a < 2; ++a) {
        acc[a][0] = (f32x4){0.f, 0.f, 0.f, 0.f};
        acc[a][1] = (f32x4){0.f, 0.f, 0.f, 0.f};
    }

    int nkt = (L + 63) >> 6;
    for (int t = 0; t < nkt; ++t) {
        int kt = t * 64;
        __syncthreads();  // LDS tile t ready

        short8b kf[4];
#pragma unroll
        for (int kn = 0; kn < 4; ++kn)
            kf[kn] = *(const short8b*)&Klds[kn * 16 + lrow][lgrp * 8];
        short8b vf[2][2];
#pragma unroll
        for (int dsub = 0; dsub < 2; ++dsub)
#pragma unroll
            for (int kh = 0; kh < 2; ++kh)
                vf[dsub][kh] = *(const short8b*)&Vt[dsub * 16 + lrow][kh * 32 + lgrp * 8];

        // prefetch tile t+1 global -> regs (latency hidden under compute)
        bool more = (t + 1) < nkt;
        short8b kreg;
        ushort4 vreg0, vreg1;
        if (more) {
            int ktn = kt + 64;
            int kr = (ktn + skey) < L ? (ktn + skey) : L - 1;
            kreg = *(const short8b*)&Kb[(size_t)(s0 + kr) * 256 + h * 32 + skc];
            int vr0 = (ktn + vkey) < L ? (ktn + vkey) : L - 1;
            int vr1 = (ktn + vkey + 32) < L ? (ktn + vkey + 32) : L - 1;
            vreg0 = *(const ushort4*)&Vb[(size_t)(s0 + vr0) * 256 + h * 32 + vd4];
            vreg1 = *(const ushort4*)&Vb[(size_t)(s0 + vr1) * 256 + h * 32 + vd4];
        }

        bool tail = (kt + 64 > L);
        short8b pf[2][2];
#pragma unroll
        for (int qm = 0; qm < 2; ++qm) {
            f32x4 s[4];
#pragma unroll
            for (int kn = 0; kn < 4; ++kn)
                s[kn] = __builtin_amdgcn_mfma_f32_16x16x32_bf16(
                    kf[kn], qf[qm], (f32x4){0.f, 0.f, 0.f, 0.f}, 0, 0, 0);
            if (tail) {
#pragma unroll
                for (int kn = 0; kn < 4; ++kn)
#pragma unroll
                    for (int r = 0; r < 4; ++r) {
                        int key = kt + kn * 16 + lgrp * 4 + r;
                        if (key >= L) s[kn][r] = -INFINITY;
                    }
            }
            // static-max softmax numerator: pv = exp2(s), fp32-safe via clamp
            float ps = lrun[qm];
#pragma unroll
            for (int kn = 0; kn < 4; ++kn)
#pragma unroll
                for (int r = 0; r < 4; ++r) {
                    float pv = exp2f(fminf(s[kn][r], 80.f));
                    s[kn][r] = pv;
                    ps += pv;
                }
            lrun[qm] = ps;
            pf[qm][0] = pack2v(s[0], s[1]);
            pf[qm][1] = pack2v(s[2], s[3]);
        }

        // PV: O^T += V^T P^T (sigma-permuted key order on both sides)
#pragma unroll
        for (int qm = 0; qm < 2; ++qm)
#pragma unroll
            for (int dsub = 0; dsub < 2; ++dsub) {
                acc[qm][dsub] = __builtin_amdgcn_mfma_f32_16x16x32_bf16(
                    vf[dsub][0], pf[qm][0], acc[qm][dsub], 0, 0, 0);
                acc[qm][dsub] = __builtin_amdgcn_mfma_f32_16x16x32_bf16(
                    vf[dsub][1], pf[qm][1], acc[qm][dsub], 0, 0, 0);
            }

        __syncthreads();  // all waves done reading tile t
        if (more) {
            *(short8b*)&Klds[skey][skc] = kreg;
            Vt[vd4 + 0][vcol0] = vreg0.x; Vt[vd4 + 1][vcol0] = vreg0.y;
            Vt[vd4 + 2][vcol0] = vreg0.z; Vt[vd4 + 3][vcol0] = vreg0.w;
            Vt[vd4 + 0][vcol1] = vreg1.x; Vt[vd4 + 1][vcol1] = vreg1.y;
            Vt[vd4 + 2][vcol1] = vreg1.z; Vt[vd4 + 3][vcol1] = vreg1.w;
        }
    }

    // epilogue: reduce row sums (once), normalize, store bf16
#pragma unroll
    for (int qm = 0; qm < 2; ++qm) {
        int q = qbase + qm * 16 + lrow;
        float tsum = lrun[qm];
        tsum += __shfl_xor(tsum, 16);
        tsum += __shfl_xor(tsum, 32);
        if (q >= L) continue;
        float inv = 1.f / tsum;
        unsigned short* dst = ctxb + (size_t)(s0 + q) * 256 + h * 32;
#pragma unroll
        for (int dsub = 0; dsub < 2; ++dsub) {
#pragma unroll
            for (int rp = 0; rp < 4; rp += 2) {
                *(unsigned int*)&dst[dsub * 16 + lgrp * 4 + rp] =
                    pk2(acc[qm][dsub][rp] * inv, acc[qm][dsub][rp + 1] * inv);
            }
        }
    }
}

// ---------------- per-graph LN stats: 4 partial blocks per graph -----------
__global__ __launch_bounds__(256) void k_stats_part(
    const float* __restrict__ hbuf, const int* __restrict__ starts,
    const int* __restrict__ counts, float* __restrict__ part) {
    int g = blockIdx.x, qq = blockIdx.y;
    int s0 = starts[g], cnt = counts[g];
    int cq = (cnt + 3) >> 2;
    int r0 = qq * cq;
    int r1 = min(cnt, r0 + cq);

    float sum = 0.f, sq = 0.f;
    if (r0 < r1) {
        const float4* p = (const float4*)(hbuf + (size_t)(s0 + r0) * D_EMB);
        size_t n4 = (size_t)(r1 - r0) * (D_EMB / 4);
        for (size_t i = threadIdx.x; i < n4; i += 256) {
            float4 v = p[i];
            sum += v.x + v.y + v.z + v.w;
            sq += v.x * v.x + v.y * v.y + v.z * v.z + v.w * v.w;
        }
    }
#pragma unroll
    for (int o = 32; o > 0; o >>= 1) {
        sum += __shfl_down(sum, o);
        sq += __shfl_down(sq, o);
    }
    __shared__ float ssum[4], ssq[4];
    int wid = threadIdx.x >> 6, lane = threadIdx.x & 63;
    if (lane == 0) { ssum[wid] = sum; ssq[wid] = sq; }
    __syncthreads();
    if (threadIdx.x == 0) {
        float S = 0.f, Q = 0.f;
#pragma unroll
        for (int w = 0; w < 4; ++w) { S += ssum[w]; Q += ssq[w]; }
        part[(g * 4 + qq) * 2] = S;
        part[(g * 4 + qq) * 2 + 1] = Q;
    }
}

__global__ void k_stats_final(const float* __restrict__ part,
                              const int* __restrict__ counts,
                              float* __restrict__ stats) {
    int g = threadIdx.x;
    if (g >= NG) return;
    float S = 0.f, Q = 0.f;
#pragma unroll
    for (int i = 0; i < 4; ++i) {
        S += part[(g * 4 + i) * 2];
        Q += part[(g * 4 + i) * 2 + 1];
    }
    float norm = (float)counts[g] * (float)D_EMB;
    float mean = S / norm;
    float var = Q / norm - mean * mean;
    stats[2 * g] = mean;
    stats[2 * g + 1] = rsqrtf(var + 1e-5f);
}

// ---------------- LN apply + exact GELU, in place --------------------------
__global__ void k_ln_gelu(float* __restrict__ h, const int* __restrict__ batch,
                          const float* __restrict__ stats, const float* __restrict__ lw,
                          const float* __restrict__ lb, int n) {
    int idx = blockIdx.x * blockDim.x + threadIdx.x;
    if (idx >= n * (D_EMB / 4)) return;
    int row = idx >> 6;
    int c4 = idx & 63;
    int g = batch[row];
    float mean = stats[2 * g], inv = stats[2 * g + 1];
    float4 v = *(float4*)&h[(size_t)idx * 4];
    float4 wv = *(const float4*)&lw[c4 * 4];
    float4 bv = *(const float4*)&lb[c4 * 4];
    float y;
    y = (v.x - mean) * inv * wv.x + bv.x; v.x = 0.5f * y * (1.f + erff(y * 0.70710678118f));
    y = (v.y - mean) * inv * wv.y + bv.y; v.y = 0.5f * y * (1.f + erff(y * 0.70710678118f));
    y = (v.z - mean) * inv * wv.z + bv.z; v.z = 0.5f * y * (1.f + erff(y * 0.70710678118f));
    y = (v.w - mean) * inv * wv.w + bv.w; v.w = 0.5f * y * (1.f + erff(y * 0.70710678118f));
    *(float4*)&h[(size_t)idx * 4] = v;
}

// ---------------- launch ----------------------------------------------------
extern "C" void kernel_launch(void* const* d_in, const int* in_sizes, int n_in,
                              void* d_out, int out_size, void* d_ws, size_t ws_size,
                              hipStream_t stream) {
    const float* x     = (const float*)d_in[0];
    const int*   batch = (const int*)d_in[1];
    const float* in_w  = (const float*)d_in[2];
    const float* in_b  = (const float*)d_in[3];
    const float* out_w = (const float*)d_in[4];
    const float* out_b = (const float*)d_in[5];
    const float* ln_w  = (const float*)d_in[6];
    const float* ln_b  = (const float*)d_in[7];
    int N = in_sizes[1];
    float* out = (float*)d_out;

    char* ws = (char*)d_ws;
    int*   starts = (int*)ws;                         // 64 ints
    int*   counts = starts + 64;                      // 64 ints
    float* stats  = (float*)(ws + 512);               // 128 floats
    float* part   = (float*)(ws + 1024);              // 512 floats
    unsigned short* xb   = (unsigned short*)(ws + 3072);
    unsigned short* wb1  = xb + (size_t)N * 256;
    unsigned short* wb2  = wb1 + 768 * 256;
    unsigned short* Qb   = wb2 + 256 * 256;
    unsigned short* Kb   = Qb + (size_t)N * 256;
    unsigned short* Vb   = Kb + (size_t)N * 256;
    unsigned short* ctxb = Vb + (size_t)N * 256;

    k_starts<<<(N + 255) / 256, 256, 0, stream>>>(batch, N, starts);
    k_counts<<<1, 64, 0, stream>>>(starts, N, counts);

    int n4x = N * 64;
    k_f2bf4<<<(n4x + 255) / 256, 256, 0, stream>>>(x, xb, n4x);
    k_f2bf4<<<(768 * 64 + 255) / 256, 256, 0, stream>>>(in_w, wb1, 768 * 64);
    k_f2bf4<<<(256 * 64 + 255) / 256, 256, 0, stream>>>(out_w, wb2, 256 * 64);

    dim3 g1((N + 127) / 128, 6);
    k_gemm<1><<<g1, 256, 0, stream>>>(xb, wb1, in_b, nullptr, nullptr,
                                      Qb, Kb, Vb, N, 768);

    k_attn5<<<dim3(NG, NHEAD, 4), 256, 0, stream>>>(Qb, Kb, Vb, starts, counts, ctxb);

    dim3 g3((N + 127) / 128, 2);
    k_gemm<0><<<g3, 256, 0, stream>>>(ctxb, wb2, out_b, x, out,
                                      nullptr, nullptr, nullptr, N, 256);

    k_stats_part<<<dim3(NG, 4), 256, 0, stream>>>(out, starts, counts, part);
    k_stats_final<<<1, 64, 0, stream>>>(part, counts, stats);

    int nv4 = N * (D_EMB / 4);
    k_ln_gelu<<<(nv4 + 255) / 256, 256, 0, stream>>>(out, batch, stats, ln_w, ln_b, N);
}